// Round 2
// baseline (168.583 us; speedup 1.0000x reference)
//
#include <hip/hip_runtime.h>
#include <math.h>

// ---------------- problem constants ----------------
#define B_TOT 8192
#define KE 400      // 16 nodes * 25 t (ecc K)
#define KR 300      // 12 nodes * 25 t (err K)
#define MEP 416     // ecc K padded to 13*32
#define MRP 320     // err K padded to 10*32

// fused_main tile: 16 batch rows per block -> 512 blocks, 26.4 KB LDS
#define ROWS 16

// LDS strides (bf16 elements), padded for bank-conflict avoidance
#define SXE_LD 424
#define SXR_LD 328
#define SEH_LD 72

// ---------------- workspace layout ----------------
// float offsets
#define OFF_BE 6528
#define OFF_BR 6784
// ushort offsets (from d_ws base viewed as ushort*), 16B-aligned
#define U_AET 14080                   // AwT_ecc [256][416] bf16
#define U_ART (U_AET + 256 * MEP)     // AwT_err [256][320] bf16
#define U_WET (U_ART + 256 * MRP)     // WeT     [64][64]  bf16

typedef __attribute__((ext_vector_type(8))) short short8;
typedef __attribute__((ext_vector_type(4))) float floatx4;

__device__ __forceinline__ float sigmoidf_(float x) { return 1.f / (1.f + __expf(-x)); }
__device__ __forceinline__ float tanhf_(float x) { float e = __expf(2.f * x); return (e - 1.f) / (e + 1.f); }
__device__ __forceinline__ unsigned short f2bf(float x) {
    unsigned u = __float_as_uint(x);
    u += 0x7fffu + ((u >> 16) & 1u);          // round-to-nearest-even
    return (unsigned short)(u >> 16);
}

// =====================================================================
// Kernel 1 (merged fold): one self-contained kernel.
//  blk 0/1  : bias_ecc / bias_err  (cvec in-block, then 1024/768-term dot,
//             scheduled FIRST so the serial dot overlaps the k-row blocks)
//  blk 2    : WeT transpose (bf16)
//  blk 3+   : one k-row of AwT per block; recomputes its own Weff rows
//             in-block from wt/W0/W1 (L2-hot, ~12K FMA amortized over 256
//             threads) -- removes the fold_temporal kernel + serialization
//             + the atomicAdd/zero-init bias path entirely.
// grid = 3 + 416 + 320 = 739 blocks x 256 threads
// =====================================================================
__global__ __launch_bounds__(256) void fold_all(
    const float* __restrict__ wt_ecc, const float* __restrict__ bt_ecc,
    const float* __restrict__ wt_err, const float* __restrict__ bt_err,
    const float* __restrict__ W0_ecc, const float* __restrict__ W1_ecc, const float* __restrict__ b_ecc,
    const float* __restrict__ W0_err, const float* __restrict__ W1_err, const float* __restrict__ b_err,
    const float* __restrict__ Wp_ecc, const float* __restrict__ bp_ecc,
    const float* __restrict__ Wp_err, const float* __restrict__ bp_err,
    const float* __restrict__ We,
    float* __restrict__ wsf, unsigned short* __restrict__ wsu)
{
    const int blk = blockIdx.x;
    const int tid = threadIdx.x;
    const int cq = tid >> 6;    // 0..3  (c-chunk of 8)
    const int g  = tid & 63;

    __shared__ float red0[4][64];
    __shared__ float red1[4][64];
    __shared__ float sw0[64];
    __shared__ float sw1[64];

    if (blk < 2) {
        // ---- bias block: cvec[g] = b[g] + sum_{c,t} bt[c]*(W0-W1)[ct][g] ----
        const bool is_err = (blk == 1);
        const float* bt = is_err ? bt_err : bt_ecc;
        const float* W0 = is_err ? W0_err : W0_ecc;
        const float* W1 = is_err ? W1_err : W1_ecc;
        const float* bb = is_err ? b_err : b_ecc;
        const float* Wp = is_err ? Wp_err : Wp_ecc;
        const float* bp = is_err ? bp_err : bp_ecc;
        const int J = (is_err ? 12 : 16) * 64;
        float s = 0.f;
        #pragma unroll
        for (int c8 = 0; c8 < 8; ++c8) {
            const int c = cq * 8 + c8;
            const float btc = bt[c];
            #pragma unroll
            for (int t = 0; t < 25; ++t) {
                const int ct = (c * 25 + t) * 64 + g;
                s = fmaf(btc, W0[ct] - W1[ct], s);
            }
        }
        red0[cq][g] = s;
        __syncthreads();
        if (tid < 64)
            sw0[g] = bb[g] + red0[0][g] + red0[1][g] + red0[2][g] + red0[3][g];
        __syncthreads();
        // ---- bias[h] = bp[h] + sum_j cvec[j&63] * Wp[j*256+h] ----
        const int h = tid;
        float a0 = 0.f, a1 = 0.f, a2 = 0.f, a3 = 0.f;
        for (int j = 0; j < J; j += 4) {
            a0 = fmaf(sw0[(j + 0) & 63], Wp[(size_t)(j + 0) * 256 + h], a0);
            a1 = fmaf(sw0[(j + 1) & 63], Wp[(size_t)(j + 1) * 256 + h], a1);
            a2 = fmaf(sw0[(j + 2) & 63], Wp[(size_t)(j + 2) * 256 + h], a2);
            a3 = fmaf(sw0[(j + 3) & 63], Wp[(size_t)(j + 3) * 256 + h], a3);
        }
        wsf[(is_err ? OFF_BR : OFF_BE) + h] = bp[h] + ((a0 + a1) + (a2 + a3));
    } else if (blk == 2) {
        // ---- WeT[e][d] = We[d][e], bf16 ----
        for (int it = 0; it < 16; ++it) {
            const int idx = it * 256 + tid;
            const int e = idx >> 6, d = idx & 63;
            wsu[U_WET + e * 64 + d] = f2bf(We[d * 64 + e]);
        }
    } else {
        // ---- one k-row of AwT ----
        const int kb = blk - 3;
        const bool is_err = (kb >= MEP);
        const int k  = is_err ? kb - MEP : kb;
        const int KK = is_err ? KR : KE;
        const int MP = is_err ? MRP : MEP;
        const float* wt = is_err ? wt_err : wt_ecc;
        const float* W0 = is_err ? W0_err : W0_ecc;
        const float* W1 = is_err ? W1_err : W1_ecc;
        const float* Wp = is_err ? Wp_err : Wp_ecc;
        const int ubase = is_err ? U_ART : U_AET;

        float s = 0.f;
        if (k < KK) {             // block-uniform branch (k uniform per block)
            const int v = k / 25, tin = k % 25;
            // recompute Weff0/Weff1 row tin in-block
            const int t0 = tin > 0 ? tin - 1 : 0;
            const int t1 = tin < 24 ? tin + 1 : 24;
            float s0 = 0.f, s1 = 0.f;
            #pragma unroll
            for (int c8 = 0; c8 < 8; ++c8) {
                const int c = cq * 8 + c8;
                for (int t = t0; t <= t1; ++t) {
                    const int kk = tin - t + 1;          // 0..2
                    const float w = wt[c * 3 + kk];
                    const int ct = (c * 25 + t) * 64 + g;
                    s0 = fmaf(w, W0[ct], s0);
                    s1 = fmaf(w, W1[ct], s1);
                }
            }
            red0[cq][g] = s0;
            red1[cq][g] = s1;
            __syncthreads();
            if (tid < 64)
                sw0[g] = red0[0][g] + red0[1][g] + red0[2][g] + red0[3][g];
            else if (tid < 128)
                sw1[tid - 64] = red1[0][tid - 64] + red1[1][tid - 64] + red1[2][tid - 64] + red1[3][tid - 64];
            __syncthreads();

            const int nv = is_err ? 12 : 16;
            const int vp = (v + 1) % nv;
            const int vm = (v + nv - 1) % nv;
            const int h = tid;
            #pragma unroll 4
            for (int gg = 0; gg < 64; ++gg) {
                s = fmaf(sw0[gg], Wp[(v * 64 + gg) * 256 + h], s);
                s = fmaf(-0.5f * sw1[gg], Wp[(vp * 64 + gg) * 256 + h] + Wp[(vm * 64 + gg) * 256 + h], s);
            }
        }
        wsu[ubase + (size_t)tid * MP + k] = f2bf(s);
    }
}

// =====================================================================
// Kernel 2 (fused): per-block 16 batch rows, 4 waves.
//   - stage X_ecc/X_err/ehr fp32->bf16 into LDS (26.4 KB)
//   - MFMA 16x16x32 bf16: ecc_g, err_g (16x256), ehr_p (16x64)
//   - epilogue entirely in registers + shfl
// grid = 512 blocks x 256 threads, __launch_bounds__(256,4) -> 4 blocks/CU
// =====================================================================
__global__ __launch_bounds__(256, 4) void fused_main(
    const float* __restrict__ ecc, const float* __restrict__ err, const float* __restrict__ ehr,
    const float* __restrict__ wsf, const unsigned short* __restrict__ wsu,
    const float* __restrict__ Wa, const float* __restrict__ ba,
    const float* __restrict__ be_, const float* __restrict__ Wf2, const float* __restrict__ bf2,
    float* __restrict__ out)
{
    const unsigned short* awt_e = wsu + U_AET;
    const unsigned short* awt_r = wsu + U_ART;
    const unsigned short* wet   = wsu + U_WET;
    const float* biasE = wsf + OFF_BE;
    const float* biasR = wsf + OFF_BR;

    __shared__ __align__(16) char smem[ROWS * SXE_LD * 2 + ROWS * SXR_LD * 2 + ROWS * SEH_LD * 2];
    unsigned short* sxe = (unsigned short*)smem;          // [16][SXE_LD]
    unsigned short* sxr = sxe + ROWS * SXE_LD;            // [16][SXR_LD]
    unsigned short* seh = sxr + ROWS * SXR_LD;            // [16][SEH_LD]
    // epilogue scratch overlays sxe (used only after the post-MFMA barrier)
    float* pa_part = (float*)smem;                        // [4][16]
    float* at_arr  = pa_part + 64;                        // [16]
    float* po_part = at_arr + 16;                         // [4][16]

    const int tid = threadIdx.x;
    const int row0 = blockIdx.x * ROWS;

    // ---- stage X_ecc: 16 rows x 106 quads (real quads < 100) ----
    for (int it = 0; it < 7; ++it) {
        const int f = it * 256 + tid;
        if (f < ROWS * 106) {
            const int r = f / 106, q = f - r * 106;
            float4 v = make_float4(0.f, 0.f, 0.f, 0.f);
            if (q < 100) v = *(const float4*)(ecc + (size_t)(row0 + r) * KE + q * 4);
            const unsigned p0 = (unsigned)f2bf(v.x) | ((unsigned)f2bf(v.y) << 16);
            const unsigned p1 = (unsigned)f2bf(v.z) | ((unsigned)f2bf(v.w) << 16);
            *(uint2*)&sxe[r * SXE_LD + q * 4] = make_uint2(p0, p1);
        }
    }
    // ---- stage X_err: 16 rows x 82 quads (real quads < 75) ----
    for (int it = 0; it < 6; ++it) {
        const int f = it * 256 + tid;
        if (f < ROWS * 82) {
            const int r = f / 82, q = f - r * 82;
            float4 v = make_float4(0.f, 0.f, 0.f, 0.f);
            if (q < 75) v = *(const float4*)(err + (size_t)(row0 + r) * KR + q * 4);
            const unsigned p0 = (unsigned)f2bf(v.x) | ((unsigned)f2bf(v.y) << 16);
            const unsigned p1 = (unsigned)f2bf(v.z) | ((unsigned)f2bf(v.w) << 16);
            *(uint2*)&sxr[r * SXR_LD + q * 4] = make_uint2(p0, p1);
        }
    }
    // ---- stage ehr: 16 rows x 16 quads exactly (one iteration) ----
    {
        const int r = tid >> 4, q = tid & 15;
        const float4 v = *(const float4*)(ehr + (size_t)(row0 + r) * 64 + q * 4);
        const unsigned p0 = (unsigned)f2bf(v.x) | ((unsigned)f2bf(v.y) << 16);
        const unsigned p1 = (unsigned)f2bf(v.z) | ((unsigned)f2bf(v.w) << 16);
        *(uint2*)&seh[r * SEH_LD + q * 4] = make_uint2(p0, p1);
    }
    __syncthreads();

    const int wv = tid >> 6, lane = tid & 63;
    const int lm = lane & 15, lq = lane >> 4;
    const int n0 = wv * 64;

    floatx4 accE[4], accR[4], accH;
    accH = (floatx4){0.f, 0.f, 0.f, 0.f};
    #pragma unroll
    for (int nt = 0; nt < 4; ++nt) {
        accE[nt] = (floatx4){0.f, 0.f, 0.f, 0.f};
        accR[nt] = (floatx4){0.f, 0.f, 0.f, 0.f};
    }

    // ---- ehr_p = ehr @ We : wave handles e-slab wv (e = 16*wv + lm) ----
    #pragma unroll
    for (int kc = 0; kc < 2; ++kc) {
        const short8 b = *(const short8*)(wet + (wv * 16 + lm) * 64 + kc * 32 + lq * 8);
        const short8 a = *(const short8*)&seh[lm * SEH_LD + kc * 32 + lq * 8];
        accH = __builtin_amdgcn_mfma_f32_16x16x32_bf16(a, b, accH, 0, 0, 0);
    }
    // ---- ecc branch: 13 k-chunks ----
    #pragma unroll
    for (int kc = 0; kc < 13; ++kc) {
        const short8 a0 = *(const short8*)&sxe[lm * SXE_LD + kc * 32 + lq * 8];
        #pragma unroll
        for (int nt = 0; nt < 4; ++nt) {
            const short8 b = *(const short8*)(awt_e + (size_t)(n0 + nt * 16 + lm) * MEP + kc * 32 + lq * 8);
            accE[nt] = __builtin_amdgcn_mfma_f32_16x16x32_bf16(a0, b, accE[nt], 0, 0, 0);
        }
    }
    // ---- err branch: 10 k-chunks ----
    #pragma unroll
    for (int kc = 0; kc < 10; ++kc) {
        const short8 a0 = *(const short8*)&sxr[lm * SXR_LD + kc * 32 + lq * 8];
        #pragma unroll
        for (int nt = 0; nt < 4; ++nt) {
            const short8 b = *(const short8*)(awt_r + (size_t)(n0 + nt * 16 + lm) * MRP + kc * 32 + lq * 8);
            accR[nt] = __builtin_amdgcn_mfma_f32_16x16x32_bf16(a0, b, accR[nt], 0, 0, 0);
        }
    }

    // ---- per-lane epilogue constants (L2-hot scalar loads) ----
    float bE[4], bR[4], wa[4], wf[4];
    #pragma unroll
    for (int nt = 0; nt < 4; ++nt) {
        const int h = n0 + nt * 16 + lm;
        bE[nt] = biasE[h]; bR[nt] = biasR[h]; wa[nt] = Wa[h]; wf[nt] = Wf2[h];
    }
    const int e_lane = wv * 16 + lm;
    const float eh_be = be_[e_lane];
    const float eh_wf = Wf2[256 + e_lane];

    // ---- pass 1: attention logits, pure register + shfl ----
    float pa_lane[4];
    #pragma unroll
    for (int rg = 0; rg < 4; ++rg) {
        float s = 0.f;
        #pragma unroll
        for (int nt = 0; nt < 4; ++nt) {
            const float ev = accE[nt][rg] + bE[nt];
            const float rv = accR[nt][rg] + bR[nt];
            s = fmaf(tanhf_(ev + rv), wa[nt], s);
        }
        s += __shfl_xor(s, 1, 64); s += __shfl_xor(s, 2, 64);
        s += __shfl_xor(s, 4, 64); s += __shfl_xor(s, 8, 64);
        pa_lane[rg] = s;
    }

    __syncthreads();   // all staging-LDS reads complete; safe to overlay scratch
    if (lm == 0) {
        #pragma unroll
        for (int rg = 0; rg < 4; ++rg)
            pa_part[wv * 16 + lq * 4 + rg] = pa_lane[rg];
    }
    __syncthreads();
    if (tid < 16)
        at_arr[tid] = sigmoidf_(pa_part[tid] + pa_part[16 + tid] + pa_part[32 + tid] + pa_part[48 + tid] + ba[0]);
    __syncthreads();

    // ---- pass 2: fused + EHR dot with Wf2, register + shfl ----
    float po_lane[4];
    #pragma unroll
    for (int rg = 0; rg < 4; ++rg) {
        const int r = lq * 4 + rg;
        const float at = at_arr[r];
        const float om = 1.f - at;
        float s = 0.f;
        #pragma unroll
        for (int nt = 0; nt < 4; ++nt) {
            const float ev = accE[nt][rg] + bE[nt];
            const float rv = accR[nt][rg] + bR[nt];
            s = fmaf(fmaxf(at * ev + om * rv, 0.f), wf[nt], s);
        }
        s = fmaf(fmaxf(accH[rg] + eh_be, 0.f), eh_wf, s);
        s += __shfl_xor(s, 1, 64); s += __shfl_xor(s, 2, 64);
        s += __shfl_xor(s, 4, 64); s += __shfl_xor(s, 8, 64);
        po_lane[rg] = s;
    }
    if (lm == 0) {
        #pragma unroll
        for (int rg = 0; rg < 4; ++rg)
            po_part[wv * 16 + lq * 4 + rg] = po_lane[rg];
    }
    __syncthreads();
    if (tid < 16)
        out[row0 + tid] = sigmoidf_(po_part[tid] + po_part[16 + tid] + po_part[32 + tid] + po_part[48 + tid] + bf2[0]);
}

// =====================================================================
extern "C" void kernel_launch(void* const* d_in, const int* in_sizes, int n_in,
                              void* d_out, int out_size, void* d_ws, size_t ws_size,
                              hipStream_t stream)
{
    (void)in_sizes; (void)n_in; (void)out_size; (void)ws_size;
    const float* ecc    = (const float*)d_in[0];
    const float* err    = (const float*)d_in[1];
    const float* ehr    = (const float*)d_in[2];
    const float* wt_ecc = (const float*)d_in[3];
    const float* bt_ecc = (const float*)d_in[4];
    const float* wt_err = (const float*)d_in[5];
    const float* bt_err = (const float*)d_in[6];
    const float* W0_ecc = (const float*)d_in[7];
    const float* W1_ecc = (const float*)d_in[8];
    const float* b_ecc  = (const float*)d_in[9];
    const float* W0_err = (const float*)d_in[10];
    const float* W1_err = (const float*)d_in[11];
    const float* b_err  = (const float*)d_in[12];
    const float* Wp_ecc = (const float*)d_in[13];
    const float* bp_ecc = (const float*)d_in[14];
    const float* Wp_err = (const float*)d_in[15];
    const float* bp_err = (const float*)d_in[16];
    const float* Wa     = (const float*)d_in[17];
    const float* ba     = (const float*)d_in[18];
    const float* We     = (const float*)d_in[19];
    const float* be     = (const float*)d_in[20];
    const float* Wf2    = (const float*)d_in[21];
    const float* bf2    = (const float*)d_in[22];
    float* wsf = (float*)d_ws;
    unsigned short* wsu = (unsigned short*)d_ws;
    float* out = (float*)d_out;

    fold_all<<<dim3(3 + MEP + MRP), dim3(256), 0, stream>>>(
        wt_ecc, bt_ecc, wt_err, bt_err,
        W0_ecc, W1_ecc, b_ecc, W0_err, W1_err, b_err,
        Wp_ecc, bp_ecc, Wp_err, bp_err, We, wsf, wsu);
    fused_main<<<dim3(B_TOT / ROWS), dim3(256), 0, stream>>>(
        ecc, err, ehr, wsf, wsu, Wa, ba, be, Wf2, bf2, out);
}

// Round 3
// 152.856 us; speedup vs baseline: 1.1029x; 1.1029x over previous
//
#include <hip/hip_runtime.h>
#include <math.h>

// ---------------- problem constants ----------------
#define B_TOT 8192
#define KE 400      // 16 nodes * 25 t (ecc K)
#define KR 300      // 12 nodes * 25 t (err K)
#define MEP 416     // ecc K padded to 13*32
#define MRP 320     // err K padded to 10*32

#define ROWS 16     // fused_main: 16 batch rows per block -> 512 blocks

// ---------------- workspace layout ----------------
// float offsets
#define OFF_WEFF0E 0
#define OFF_WEFF1E 1600
#define OFF_WEFF0R 3200
#define OFF_WEFF1R 4800
#define OFF_CVE    6400
#define OFF_CVR    6464
#define OFF_BE     6528
#define OFF_BR     6784
// ushort offsets (from d_ws base viewed as ushort*), 16B-aligned
#define U_AET 14080                   // AwT_ecc [256][416] bf16
#define U_ART (U_AET + 256 * MEP)     // AwT_err [256][320] bf16  (=120576)
#define U_WET (U_ART + 256 * MRP)     // WeT     [64][64]  bf16   (=202496)
#define U_XE  (U_WET + 64 * 64)       // Xe [8192][416] bf16      (=206592)
#define U_XR  (U_XE + 8192 * MEP)     // Xr [8192][320] bf16      (=3614464)
#define U_XH  (U_XR + 8192 * MRP)     // Xh [8192][64]  bf16      (=6235904)

// conversion chunk counts (8 bf16 per chunk)
#define TCE (8192 * 52)   // 416/8 per row
#define TCR (8192 * 40)   // 320/8 per row
#define TCH (8192 * 8)    // 64/8  per row
#define CONVB 768

typedef __attribute__((ext_vector_type(8))) short short8;
typedef __attribute__((ext_vector_type(4))) float floatx4;

__device__ __forceinline__ float sigmoidf_(float x) { return 1.f / (1.f + __expf(-x)); }
__device__ __forceinline__ float tanhf_(float x) { float e = __expf(2.f * x); return (e - 1.f) / (e + 1.f); }
__device__ __forceinline__ unsigned short f2bf(float x) {
    unsigned u = __float_as_uint(x);
    u += 0x7fffu + ((u >> 16) & 1u);          // round-to-nearest-even
    return (unsigned short)(u >> 16);
}
__device__ __forceinline__ uint4 pack8(float4 a, float4 b) {
    uint4 r;
    r.x = (unsigned)f2bf(a.x) | ((unsigned)f2bf(a.y) << 16);
    r.y = (unsigned)f2bf(a.z) | ((unsigned)f2bf(a.w) << 16);
    r.z = (unsigned)f2bf(b.x) | ((unsigned)f2bf(b.y) << 16);
    r.w = (unsigned)f2bf(b.z) | ((unsigned)f2bf(b.w) << 16);
    return r;
}

// =====================================================================
// Kernel 1: fold Conv1d into W0/W1 -> Weff [25][64] per (branch, order),
// cvec[64], and zero the bias accumulators.  grid = 103 x 256
// =====================================================================
__global__ __launch_bounds__(256) void fold_temporal(
    const float* __restrict__ wt_ecc, const float* __restrict__ bt_ecc,
    const float* __restrict__ wt_err, const float* __restrict__ bt_err,
    const float* __restrict__ W0_ecc, const float* __restrict__ W1_ecc, const float* __restrict__ b_ecc,
    const float* __restrict__ W0_err, const float* __restrict__ W1_err, const float* __restrict__ b_err,
    float* __restrict__ ws)
{
    const int blk = blockIdx.x;
    const int tid = threadIdx.x;
    const int cq = tid >> 6;    // 0..3  (c-chunk of 8)
    const int g  = tid & 63;

    __shared__ float red[4][64];

    if (blk < 100) {
        const int m = blk / 25;       // 0: W0_ecc, 1: W1_ecc, 2: W0_err, 3: W1_err
        const int tin = blk % 25;
        const bool is_err = (m >= 2);
        const float* wt = is_err ? wt_err : wt_ecc;
        const float* W = (m & 1) ? (is_err ? W1_err : W1_ecc) : (is_err ? W0_err : W0_ecc);
        const int t0 = tin > 0 ? tin - 1 : 0;
        const int t1 = tin < 24 ? tin + 1 : 24;
        float s = 0.f;
        #pragma unroll
        for (int c8 = 0; c8 < 8; ++c8) {
            const int c = cq * 8 + c8;
            for (int t = t0; t <= t1; ++t) {
                const int k = tin - t + 1;           // 0..2
                s = fmaf(wt[c * 3 + k], W[(c * 25 + t) * 64 + g], s);
            }
        }
        red[cq][g] = s;
        __syncthreads();
        if (tid < 64)
            ws[m * 1600 + tin * 64 + g] = red[0][g] + red[1][g] + red[2][g] + red[3][g];
    } else if (blk < 102) {
        const bool is_err = (blk == 101);
        const float* bt = is_err ? bt_err : bt_ecc;
        const float* W0 = is_err ? W0_err : W0_ecc;
        const float* W1 = is_err ? W1_err : W1_ecc;
        const float* bb = is_err ? b_err : b_ecc;
        float s = 0.f;
        #pragma unroll
        for (int c8 = 0; c8 < 8; ++c8) {
            const int c = cq * 8 + c8;
            const float btc = bt[c];
            #pragma unroll
            for (int t = 0; t < 25; ++t) {
                const int ct = (c * 25 + t) * 64 + g;
                s = fmaf(btc, W0[ct] - W1[ct], s);
            }
        }
        red[cq][g] = s;
        __syncthreads();
        if (tid < 64)
            ws[(is_err ? OFF_CVR : OFF_CVE) + g] =
                bb[g] + red[0][g] + red[1][g] + red[2][g] + red[3][g];
    } else {
        // zero bias accumulators for fold_graph's atomicAdd
        ws[OFF_BE + tid] = 0.f;
        ws[OFF_BR + tid] = 0.f;
    }
}

// =====================================================================
// Kernel 2: fold Weff + ring stencil + Wp -> AwT (bf16, transposed, padded),
// biases (fp32, 16-way split + atomicAdd), WeT, AND (new) X conversion:
// ecc/err/ehr fp32 -> zero-padded bf16 arrays Xe/Xr/Xh.  The conversion
// blocks are pure streaming and ride the idle memory pipe of the
// latency-bound fold blocks (fold_graph runs at ~315 GB/s otherwise).
// grid = 769 + 768 = 1537 blocks x 256 threads
// =====================================================================
__global__ __launch_bounds__(256) void fold_graph(
    const float* __restrict__ Wp_ecc, const float* __restrict__ bp_ecc,
    const float* __restrict__ Wp_err, const float* __restrict__ bp_err,
    const float* __restrict__ We,
    const float* __restrict__ ecc, const float* __restrict__ err, const float* __restrict__ ehr,
    float* __restrict__ wsf, unsigned short* __restrict__ wsu)
{
    const int blk = blockIdx.x;
    const int h = threadIdx.x;

    if (blk < MEP) {
        const int k = blk;
        float s = 0.f;
        if (k < KE) {
            const int v = k / 25, tin = k % 25;
            const int vp = (v + 1) & 15, vm = (v + 15) & 15;
            const float* w0 = wsf + OFF_WEFF0E + tin * 64;
            const float* w1 = wsf + OFF_WEFF1E + tin * 64;
            #pragma unroll 4
            for (int g = 0; g < 64; ++g) {
                s = fmaf(w0[g], Wp_ecc[(v * 64 + g) * 256 + h], s);
                s = fmaf(-0.5f * w1[g], Wp_ecc[(vp * 64 + g) * 256 + h] + Wp_ecc[(vm * 64 + g) * 256 + h], s);
            }
        }
        wsu[U_AET + (size_t)h * MEP + k] = f2bf(s);
    } else if (blk < MEP + MRP) {
        const int k = blk - MEP;
        float s = 0.f;
        if (k < KR) {
            const int v = k / 25, tin = k % 25;
            const int vp = (v + 1) % 12, vm = (v + 11) % 12;
            const float* w0 = wsf + OFF_WEFF0R + tin * 64;
            const float* w1 = wsf + OFF_WEFF1R + tin * 64;
            #pragma unroll 4
            for (int g = 0; g < 64; ++g) {
                s = fmaf(w0[g], Wp_err[(v * 64 + g) * 256 + h], s);
                s = fmaf(-0.5f * w1[g], Wp_err[(vp * 64 + g) * 256 + h] + Wp_err[(vm * 64 + g) * 256 + h], s);
            }
        }
        wsu[U_ART + (size_t)h * MRP + k] = f2bf(s);
    } else if (blk < MEP + MRP + 16) {
        // bias_ecc: 1024 (v,g) terms split into 16 chunks of 64 (parallel!)
        const int i = blk - (MEP + MRP);
        const float* cv = wsf + OFF_CVE;
        float s = (i == 0) ? bp_ecc[h] : 0.f;
        #pragma unroll 4
        for (int jj = 0; jj < 64; ++jj) {
            const int j = i * 64 + jj;
            s = fmaf(cv[j & 63], Wp_ecc[(size_t)j * 256 + h], s);
        }
        atomicAdd(&wsf[OFF_BE + h], s);
    } else if (blk < MEP + MRP + 32) {
        // bias_err: 768 terms, 12 active chunks
        const int i = blk - (MEP + MRP + 16);
        const float* cv = wsf + OFF_CVR;
        float s = (i == 0) ? bp_err[h] : 0.f;
        if (i < 12) {
            #pragma unroll 4
            for (int jj = 0; jj < 64; ++jj) {
                const int j = i * 64 + jj;
                s = fmaf(cv[j & 63], Wp_err[(size_t)j * 256 + h], s);
            }
        }
        atomicAdd(&wsf[OFF_BR + h], s);
    } else if (blk < MEP + MRP + 33) {
        // WeT[e][d] = We[d][e], bf16
        for (int it = 0; it < 16; ++it) {
            const int idx = it * 256 + h;
            const int e = idx >> 6, d = idx & 63;
            wsu[U_WET + e * 64 + d] = f2bf(We[d * 64 + e]);
        }
    } else {
        // ---- X conversion: fp32 -> zero-padded bf16 (grid-stride) ----
        const int cb = blk - (MEP + MRP + 33);          // 0..CONVB-1
        const float4 z4 = make_float4(0.f, 0.f, 0.f, 0.f);
        for (int idx = cb * 256 + h; idx < TCE + TCR + TCH; idx += CONVB * 256) {
            if (idx < TCE) {
                const int row = idx / 52, c8 = idx - row * 52;
                uint4 o;
                if (c8 < 50) {
                    const float* p = ecc + (size_t)row * KE + c8 * 8;
                    o = pack8(*(const float4*)p, *(const float4*)(p + 4));
                } else {
                    o = make_uint4(0u, 0u, 0u, 0u);
                }
                *(uint4*)(wsu + U_XE + (size_t)row * MEP + c8 * 8) = o;
            } else if (idx < TCE + TCR) {
                const int j = idx - TCE;
                const int row = j / 40, c8 = j - row * 40;
                uint4 o;
                if (c8 < 37) {
                    const float* p = err + (size_t)row * KR + c8 * 8;
                    o = pack8(*(const float4*)p, *(const float4*)(p + 4));
                } else if (c8 == 37) {
                    const float* p = err + (size_t)row * KR + 296;
                    o = pack8(*(const float4*)p, z4);   // cols 296-299 valid, 300-303 pad
                } else {
                    o = make_uint4(0u, 0u, 0u, 0u);
                }
                *(uint4*)(wsu + U_XR + (size_t)row * MRP + c8 * 8) = o;
            } else {
                const int j = idx - TCE - TCR;
                const int row = j >> 3, c8 = j & 7;
                const float* p = ehr + (size_t)row * 64 + c8 * 8;
                *(uint4*)(wsu + U_XH + (size_t)row * 64 + c8 * 8) =
                    pack8(*(const float4*)p, *(const float4*)(p + 4));
            }
        }
    }
}

// =====================================================================
// Kernel 3 (fused, v2: barrier-free dataflow):
//   A-fragments load straight from the padded bf16 Xe/Xr/Xh arrays
//   (one dwordx4 per frag; 4 waves share lines via L1) -- no LDS staging,
//   no __syncthreads before the epilogue, 576 B LDS total.
//   B-fragments from AwT (L2-resident).  Epilogue in registers + shfl.
// grid = 512 blocks x 256 threads, launch_bounds(256,3)
// =====================================================================
__global__ __launch_bounds__(256, 3) void fused_main(
    const float* __restrict__ wsf, const unsigned short* __restrict__ wsu,
    const float* __restrict__ Wa, const float* __restrict__ ba,
    const float* __restrict__ be_, const float* __restrict__ Wf2, const float* __restrict__ bf2,
    float* __restrict__ out)
{
    const unsigned short* awt_e = wsu + U_AET;
    const unsigned short* awt_r = wsu + U_ART;
    const unsigned short* wet   = wsu + U_WET;
    const float* biasE = wsf + OFF_BE;
    const float* biasR = wsf + OFF_BR;

    __shared__ float pa_part[64];
    __shared__ float at_arr[16];
    __shared__ float po_part[64];

    const int tid = threadIdx.x;
    const int row0 = blockIdx.x * ROWS;
    const int wv = tid >> 6, lane = tid & 63;
    const int lm = lane & 15, lq = lane >> 4;
    const int n0 = wv * 64;

    // per-lane A row pointers (all 4 waves read the same rows -> L1 hits)
    const unsigned short* xe = wsu + U_XE + (size_t)(row0 + lm) * MEP + lq * 8;
    const unsigned short* xr = wsu + U_XR + (size_t)(row0 + lm) * MRP + lq * 8;
    const unsigned short* xh = wsu + U_XH + (size_t)(row0 + lm) * 64  + lq * 8;

    floatx4 accE[4], accR[4], accH;
    accH = (floatx4){0.f, 0.f, 0.f, 0.f};
    #pragma unroll
    for (int nt = 0; nt < 4; ++nt) {
        accE[nt] = (floatx4){0.f, 0.f, 0.f, 0.f};
        accR[nt] = (floatx4){0.f, 0.f, 0.f, 0.f};
    }

    // ---- ehr_p = ehr @ We : wave handles e-slab wv (e = 16*wv + lm) ----
    #pragma unroll
    for (int kc = 0; kc < 2; ++kc) {
        const short8 b = *(const short8*)(wet + (wv * 16 + lm) * 64 + kc * 32 + lq * 8);
        const short8 a = *(const short8*)(xh + kc * 32);
        accH = __builtin_amdgcn_mfma_f32_16x16x32_bf16(a, b, accH, 0, 0, 0);
    }
    // ---- ecc branch: 13 k-chunks ----
    #pragma unroll
    for (int kc = 0; kc < 13; ++kc) {
        const short8 a0 = *(const short8*)(xe + kc * 32);
        #pragma unroll
        for (int nt = 0; nt < 4; ++nt) {
            const short8 b = *(const short8*)(awt_e + (size_t)(n0 + nt * 16 + lm) * MEP + kc * 32 + lq * 8);
            accE[nt] = __builtin_amdgcn_mfma_f32_16x16x32_bf16(a0, b, accE[nt], 0, 0, 0);
        }
    }
    // ---- err branch: 10 k-chunks ----
    #pragma unroll
    for (int kc = 0; kc < 10; ++kc) {
        const short8 a0 = *(const short8*)(xr + kc * 32);
        #pragma unroll
        for (int nt = 0; nt < 4; ++nt) {
            const short8 b = *(const short8*)(awt_r + (size_t)(n0 + nt * 16 + lm) * MRP + kc * 32 + lq * 8);
            accR[nt] = __builtin_amdgcn_mfma_f32_16x16x32_bf16(a0, b, accR[nt], 0, 0, 0);
        }
    }

    // ---- per-lane epilogue constants (L2-hot scalar loads) ----
    float bE[4], bR[4], wa[4], wf[4];
    #pragma unroll
    for (int nt = 0; nt < 4; ++nt) {
        const int hh = n0 + nt * 16 + lm;
        bE[nt] = biasE[hh]; bR[nt] = biasR[hh]; wa[nt] = Wa[hh]; wf[nt] = Wf2[hh];
    }
    const int e_lane = wv * 16 + lm;
    const float eh_be = be_[e_lane];
    const float eh_wf = Wf2[256 + e_lane];

    // ---- pass 1: attention logits, pure register + shfl ----
    float pa_lane[4];
    #pragma unroll
    for (int rg = 0; rg < 4; ++rg) {
        float s = 0.f;
        #pragma unroll
        for (int nt = 0; nt < 4; ++nt) {
            const float ev = accE[nt][rg] + bE[nt];
            const float rv = accR[nt][rg] + bR[nt];
            s = fmaf(tanhf_(ev + rv), wa[nt], s);
        }
        s += __shfl_xor(s, 1, 64); s += __shfl_xor(s, 2, 64);
        s += __shfl_xor(s, 4, 64); s += __shfl_xor(s, 8, 64);
        pa_lane[rg] = s;
    }

    if (lm == 0) {
        #pragma unroll
        for (int rg = 0; rg < 4; ++rg)
            pa_part[wv * 16 + lq * 4 + rg] = pa_lane[rg];
    }
    __syncthreads();
    if (tid < 16)
        at_arr[tid] = sigmoidf_(pa_part[tid] + pa_part[16 + tid] + pa_part[32 + tid] + pa_part[48 + tid] + ba[0]);
    __syncthreads();

    // ---- pass 2: fused + EHR dot with Wf2, register + shfl ----
    float po_lane[4];
    #pragma unroll
    for (int rg = 0; rg < 4; ++rg) {
        const int r = lq * 4 + rg;
        const float at = at_arr[r];
        const float om = 1.f - at;
        float s = 0.f;
        #pragma unroll
        for (int nt = 0; nt < 4; ++nt) {
            const float ev = accE[nt][rg] + bE[nt];
            const float rv = accR[nt][rg] + bR[nt];
            s = fmaf(fmaxf(at * ev + om * rv, 0.f), wf[nt], s);
        }
        s = fmaf(fmaxf(accH[rg] + eh_be, 0.f), eh_wf, s);
        s += __shfl_xor(s, 1, 64); s += __shfl_xor(s, 2, 64);
        s += __shfl_xor(s, 4, 64); s += __shfl_xor(s, 8, 64);
        po_lane[rg] = s;
    }
    if (lm == 0) {
        #pragma unroll
        for (int rg = 0; rg < 4; ++rg)
            po_part[wv * 16 + lq * 4 + rg] = po_lane[rg];
    }
    __syncthreads();
    if (tid < 16)
        out[row0 + tid] = sigmoidf_(po_part[tid] + po_part[16 + tid] + po_part[32 + tid] + po_part[48 + tid] + bf2[0]);
}

// =====================================================================
extern "C" void kernel_launch(void* const* d_in, const int* in_sizes, int n_in,
                              void* d_out, int out_size, void* d_ws, size_t ws_size,
                              hipStream_t stream)
{
    (void)in_sizes; (void)n_in; (void)out_size; (void)ws_size;
    const float* ecc    = (const float*)d_in[0];
    const float* err    = (const float*)d_in[1];
    const float* ehr    = (const float*)d_in[2];
    const float* wt_ecc = (const float*)d_in[3];
    const float* bt_ecc = (const float*)d_in[4];
    const float* wt_err = (const float*)d_in[5];
    const float* bt_err = (const float*)d_in[6];
    const float* W0_ecc = (const float*)d_in[7];
    const float* W1_ecc = (const float*)d_in[8];
    const float* b_ecc  = (const float*)d_in[9];
    const float* W0_err = (const float*)d_in[10];
    const float* W1_err = (const float*)d_in[11];
    const float* b_err  = (const float*)d_in[12];
    const float* Wp_ecc = (const float*)d_in[13];
    const float* bp_ecc = (const float*)d_in[14];
    const float* Wp_err = (const float*)d_in[15];
    const float* bp_err = (const float*)d_in[16];
    const float* Wa     = (const float*)d_in[17];
    const float* ba     = (const float*)d_in[18];
    const float* We     = (const float*)d_in[19];
    const float* be     = (const float*)d_in[20];
    const float* Wf2    = (const float*)d_in[21];
    const float* bf2    = (const float*)d_in[22];
    float* wsf = (float*)d_ws;
    unsigned short* wsu = (unsigned short*)d_ws;
    float* out = (float*)d_out;

    fold_temporal<<<dim3(103), dim3(256), 0, stream>>>(
        wt_ecc, bt_ecc, wt_err, bt_err, W0_ecc, W1_ecc, b_ecc, W0_err, W1_err, b_err, wsf);
    fold_graph<<<dim3(MEP + MRP + 33 + CONVB), dim3(256), 0, stream>>>(
        Wp_ecc, bp_ecc, Wp_err, bp_err, We, ecc, err, ehr, wsf, wsu);
    fused_main<<<dim3(B_TOT / ROWS), dim3(256), 0, stream>>>(
        wsf, wsu, Wa, ba, be, Wf2, bf2, out);
}

// Round 5
// 148.775 us; speedup vs baseline: 1.1331x; 1.0274x over previous
//
#include <hip/hip_runtime.h>
#include <math.h>

// ---------------- problem constants ----------------
#define B_TOT 8192
#define KE 400      // 16 nodes * 25 t (ecc K)
#define KR 300      // 12 nodes * 25 t (err K)
#define MEP 416     // ecc K padded to 13*32
#define MRP 320     // err K padded to 10*32

#define ROWS 16     // fused_main: 16 batch rows per block -> 512 blocks

// LDS strides (bf16 elements), padded for bank-conflict avoidance
#define SXE_LD 424
#define SXR_LD 328
#define SEH_LD 72

// ---------------- workspace layout ----------------
// float offsets
#define OFF_WEFF0E 0
#define OFF_WEFF1E 1600
#define OFF_WEFF0R 3200
#define OFF_WEFF1R 4800
#define OFF_CVE    6400
#define OFF_CVR    6464
#define OFF_BE     6528
#define OFF_BR     6784
// ushort offsets (from d_ws base viewed as ushort*), 16B-aligned
#define U_AET 14080                   // AwT_ecc [256][416] bf16
#define U_ART (U_AET + 256 * MEP)     // AwT_err [256][320] bf16
#define U_WET (U_ART + 256 * MRP)     // WeT     [64][64]  bf16

typedef __attribute__((ext_vector_type(8))) short short8;
typedef __attribute__((ext_vector_type(4))) float floatx4;

__device__ __forceinline__ float sigmoidf_(float x) { return 1.f / (1.f + __expf(-x)); }
__device__ __forceinline__ float tanhf_(float x) { float e = __expf(2.f * x); return (e - 1.f) / (e + 1.f); }
__device__ __forceinline__ unsigned short f2bf(float x) {
    unsigned u = __float_as_uint(x);
    u += 0x7fffu + ((u >> 16) & 1u);          // round-to-nearest-even
    return (unsigned short)(u >> 16);
}

// =====================================================================
// Kernel 1: fold Conv1d into W0/W1 -> Weff [25][64] per (branch, order),
// cvec[64], and zero the bias accumulators.  grid = 103 x 256
// (byte-identical to the round-1 known-good version)
// =====================================================================
__global__ __launch_bounds__(256) void fold_temporal(
    const float* __restrict__ wt_ecc, const float* __restrict__ bt_ecc,
    const float* __restrict__ wt_err, const float* __restrict__ bt_err,
    const float* __restrict__ W0_ecc, const float* __restrict__ W1_ecc, const float* __restrict__ b_ecc,
    const float* __restrict__ W0_err, const float* __restrict__ W1_err, const float* __restrict__ b_err,
    float* __restrict__ ws)
{
    const int blk = blockIdx.x;
    const int tid = threadIdx.x;
    const int cq = tid >> 6;    // 0..3  (c-chunk of 8)
    const int g  = tid & 63;

    __shared__ float red[4][64];

    if (blk < 100) {
        const int m = blk / 25;       // 0: W0_ecc, 1: W1_ecc, 2: W0_err, 3: W1_err
        const int tin = blk % 25;
        const bool is_err = (m >= 2);
        const float* wt = is_err ? wt_err : wt_ecc;
        const float* W = (m & 1) ? (is_err ? W1_err : W1_ecc) : (is_err ? W0_err : W0_ecc);
        const int t0 = tin > 0 ? tin - 1 : 0;
        const int t1 = tin < 24 ? tin + 1 : 24;
        float s = 0.f;
        #pragma unroll
        for (int c8 = 0; c8 < 8; ++c8) {
            const int c = cq * 8 + c8;
            for (int t = t0; t <= t1; ++t) {
                const int k = tin - t + 1;           // 0..2
                s = fmaf(wt[c * 3 + k], W[(c * 25 + t) * 64 + g], s);
            }
        }
        red[cq][g] = s;
        __syncthreads();
        if (tid < 64)
            ws[m * 1600 + tin * 64 + g] = red[0][g] + red[1][g] + red[2][g] + red[3][g];
    } else if (blk < 102) {
        const bool is_err = (blk == 101);
        const float* bt = is_err ? bt_err : bt_ecc;
        const float* W0 = is_err ? W0_err : W0_ecc;
        const float* W1 = is_err ? W1_err : W1_ecc;
        const float* bb = is_err ? b_err : b_ecc;
        float s = 0.f;
        #pragma unroll
        for (int c8 = 0; c8 < 8; ++c8) {
            const int c = cq * 8 + c8;
            const float btc = bt[c];
            #pragma unroll
            for (int t = 0; t < 25; ++t) {
                const int ct = (c * 25 + t) * 64 + g;
                s = fmaf(btc, W0[ct] - W1[ct], s);
            }
        }
        red[cq][g] = s;
        __syncthreads();
        if (tid < 64)
            ws[(is_err ? OFF_CVR : OFF_CVE) + g] =
                bb[g] + red[0][g] + red[1][g] + red[2][g] + red[3][g];
    } else {
        // zero bias accumulators for fold_graph's atomicAdd
        ws[OFF_BE + tid] = 0.f;
        ws[OFF_BR + tid] = 0.f;
    }
}

// =====================================================================
// Kernel 2: fold Weff + ring stencil + Wp -> AwT (bf16, transposed, padded),
// biases (fp32, 16-way split + atomicAdd), WeT (bf16 transpose of We).
// grid = 416 + 320 + 16 + 16 + 1 = 769 blocks x 256 threads
// (byte-identical to the round-1 known-good version)
// =====================================================================
__global__ __launch_bounds__(256) void fold_graph(
    const float* __restrict__ Wp_ecc, const float* __restrict__ bp_ecc,
    const float* __restrict__ Wp_err, const float* __restrict__ bp_err,
    const float* __restrict__ We,
    float* __restrict__ wsf, unsigned short* __restrict__ wsu)
{
    const int blk = blockIdx.x;
    const int h = threadIdx.x;

    if (blk < MEP) {
        const int k = blk;
        float s = 0.f;
        if (k < KE) {
            const int v = k / 25, tin = k % 25;
            const int vp = (v + 1) & 15, vm = (v + 15) & 15;
            const float* w0 = wsf + OFF_WEFF0E + tin * 64;
            const float* w1 = wsf + OFF_WEFF1E + tin * 64;
            #pragma unroll 4
            for (int g = 0; g < 64; ++g) {
                s = fmaf(w0[g], Wp_ecc[(v * 64 + g) * 256 + h], s);
                s = fmaf(-0.5f * w1[g], Wp_ecc[(vp * 64 + g) * 256 + h] + Wp_ecc[(vm * 64 + g) * 256 + h], s);
            }
        }
        wsu[U_AET + (size_t)h * MEP + k] = f2bf(s);
    } else if (blk < MEP + MRP) {
        const int k = blk - MEP;
        float s = 0.f;
        if (k < KR) {
            const int v = k / 25, tin = k % 25;
            const int vp = (v + 1) % 12, vm = (v + 11) % 12;
            const float* w0 = wsf + OFF_WEFF0R + tin * 64;
            const float* w1 = wsf + OFF_WEFF1R + tin * 64;
            #pragma unroll 4
            for (int g = 0; g < 64; ++g) {
                s = fmaf(w0[g], Wp_err[(v * 64 + g) * 256 + h], s);
                s = fmaf(-0.5f * w1[g], Wp_err[(vp * 64 + g) * 256 + h] + Wp_err[(vm * 64 + g) * 256 + h], s);
            }
        }
        wsu[U_ART + (size_t)h * MRP + k] = f2bf(s);
    } else if (blk < MEP + MRP + 16) {
        // bias_ecc: 1024 (v,g) terms split into 16 chunks of 64
        const int i = blk - (MEP + MRP);
        const float* cv = wsf + OFF_CVE;
        float s = (i == 0) ? bp_ecc[h] : 0.f;
        #pragma unroll 4
        for (int jj = 0; jj < 64; ++jj) {
            const int j = i * 64 + jj;
            s = fmaf(cv[j & 63], Wp_ecc[(size_t)j * 256 + h], s);
        }
        atomicAdd(&wsf[OFF_BE + h], s);
    } else if (blk < MEP + MRP + 32) {
        // bias_err: 768 terms, 12 active chunks
        const int i = blk - (MEP + MRP + 16);
        const float* cv = wsf + OFF_CVR;
        float s = (i == 0) ? bp_err[h] : 0.f;
        if (i < 12) {
            #pragma unroll 4
            for (int jj = 0; jj < 64; ++jj) {
                const int j = i * 64 + jj;
                s = fmaf(cv[j & 63], Wp_err[(size_t)j * 256 + h], s);
            }
        }
        atomicAdd(&wsf[OFF_BR + h], s);
    } else {
        // WeT[e][d] = We[d][e], bf16
        for (int it = 0; it < 16; ++it) {
            const int idx = it * 256 + h;
            const int e = idx >> 6, d = idx & 63;
            wsu[U_WET + e * 64 + d] = f2bf(We[d * 64 + e]);
        }
    }
}

// =====================================================================
// Kernel 3 (fused, 8-wave): per-block 16 batch rows, 512 threads.
//   Each wave owns a 32-col slab (nt<2) -> 2x TLP on the latency-bound
//   L2 B-load path vs the 4-wave version; same LDS (26.4 KB), same
//   total B-traffic.  Occupancy: LDS allows 6 blocks/CU, threads 4.
// grid = 512 blocks x 512 threads
// =====================================================================
__global__ __launch_bounds__(512, 4) void fused_main(
    const float* __restrict__ ecc, const float* __restrict__ err, const float* __restrict__ ehr,
    const float* __restrict__ wsf, const unsigned short* __restrict__ wsu,
    const float* __restrict__ Wa, const float* __restrict__ ba,
    const float* __restrict__ be_, const float* __restrict__ Wf2, const float* __restrict__ bf2,
    float* __restrict__ out)
{
    const unsigned short* awt_e = wsu + U_AET;
    const unsigned short* awt_r = wsu + U_ART;
    const unsigned short* wet   = wsu + U_WET;
    const float* biasE = wsf + OFF_BE;
    const float* biasR = wsf + OFF_BR;

    __shared__ __align__(16) char smem[ROWS * SXE_LD * 2 + ROWS * SXR_LD * 2 + ROWS * SEH_LD * 2];
    unsigned short* sxe = (unsigned short*)smem;          // [16][SXE_LD]
    unsigned short* sxr = sxe + ROWS * SXE_LD;            // [16][SXR_LD]
    unsigned short* seh = sxr + ROWS * SXR_LD;            // [16][SEH_LD]
    // epilogue scratch overlays sxe (used only after the post-MFMA barrier)
    float* pa_part = (float*)smem;                        // [8][16]
    float* at_arr  = pa_part + 128;                       // [16]
    float* po_part = at_arr + 16;                         // [8][16]

    const int tid = threadIdx.x;
    const int row0 = blockIdx.x * ROWS;

    // ---- stage X_ecc: 16 rows x 106 quads (real quads < 100) ----
    for (int it = 0; it < 4; ++it) {
        const int f = it * 512 + tid;
        if (f < ROWS * 106) {
            const int r = f / 106, q = f - r * 106;
            float4 v = make_float4(0.f, 0.f, 0.f, 0.f);
            if (q < 100) v = *(const float4*)(ecc + (size_t)(row0 + r) * KE + q * 4);
            const unsigned p0 = (unsigned)f2bf(v.x) | ((unsigned)f2bf(v.y) << 16);
            const unsigned p1 = (unsigned)f2bf(v.z) | ((unsigned)f2bf(v.w) << 16);
            *(uint2*)&sxe[r * SXE_LD + q * 4] = make_uint2(p0, p1);
        }
    }
    // ---- stage X_err: 16 rows x 82 quads (real quads < 75) ----
    for (int it = 0; it < 3; ++it) {
        const int f = it * 512 + tid;
        if (f < ROWS * 82) {
            const int r = f / 82, q = f - r * 82;
            float4 v = make_float4(0.f, 0.f, 0.f, 0.f);
            if (q < 75) v = *(const float4*)(err + (size_t)(row0 + r) * KR + q * 4);
            const unsigned p0 = (unsigned)f2bf(v.x) | ((unsigned)f2bf(v.y) << 16);
            const unsigned p1 = (unsigned)f2bf(v.z) | ((unsigned)f2bf(v.w) << 16);
            *(uint2*)&sxr[r * SXR_LD + q * 4] = make_uint2(p0, p1);
        }
    }
    // ---- stage ehr: 16 rows x 16 quads ----
    if (tid < 256) {
        const int r = tid >> 4, q = tid & 15;
        const float4 v = *(const float4*)(ehr + (size_t)(row0 + r) * 64 + q * 4);
        const unsigned p0 = (unsigned)f2bf(v.x) | ((unsigned)f2bf(v.y) << 16);
        const unsigned p1 = (unsigned)f2bf(v.z) | ((unsigned)f2bf(v.w) << 16);
        *(uint2*)&seh[r * SEH_LD + q * 4] = make_uint2(p0, p1);
    }
    __syncthreads();

    const int wv = tid >> 6, lane = tid & 63;
    const int lm = lane & 15, lq = lane >> 4;
    const int n0 = wv * 32;                 // 8 waves x 32-col slabs

    floatx4 accE[2], accR[2], accH;
    accH = (floatx4){0.f, 0.f, 0.f, 0.f};
    #pragma unroll
    for (int nt = 0; nt < 2; ++nt) {
        accE[nt] = (floatx4){0.f, 0.f, 0.f, 0.f};
        accR[nt] = (floatx4){0.f, 0.f, 0.f, 0.f};
    }

    // ---- ehr_p: waves 0..3 handle e-slab wv (e = 16*wv + lm) ----
    if (wv < 4) {
        #pragma unroll
        for (int kc = 0; kc < 2; ++kc) {
            const short8 b = *(const short8*)(wet + (wv * 16 + lm) * 64 + kc * 32 + lq * 8);
            const short8 a = *(const short8*)&seh[lm * SEH_LD + kc * 32 + lq * 8];
            accH = __builtin_amdgcn_mfma_f32_16x16x32_bf16(a, b, accH, 0, 0, 0);
        }
    }
    // ---- ecc branch: 13 k-chunks x 2 n-frags ----
    #pragma unroll
    for (int kc = 0; kc < 13; ++kc) {
        const short8 a0 = *(const short8*)&sxe[lm * SXE_LD + kc * 32 + lq * 8];
        #pragma unroll
        for (int nt = 0; nt < 2; ++nt) {
            const short8 b = *(const short8*)(awt_e + (size_t)(n0 + nt * 16 + lm) * MEP + kc * 32 + lq * 8);
            accE[nt] = __builtin_amdgcn_mfma_f32_16x16x32_bf16(a0, b, accE[nt], 0, 0, 0);
        }
    }
    // ---- err branch: 10 k-chunks x 2 n-frags ----
    #pragma unroll
    for (int kc = 0; kc < 10; ++kc) {
        const short8 a0 = *(const short8*)&sxr[lm * SXR_LD + kc * 32 + lq * 8];
        #pragma unroll
        for (int nt = 0; nt < 2; ++nt) {
            const short8 b = *(const short8*)(awt_r + (size_t)(n0 + nt * 16 + lm) * MRP + kc * 32 + lq * 8);
            accR[nt] = __builtin_amdgcn_mfma_f32_16x16x32_bf16(a0, b, accR[nt], 0, 0, 0);
        }
    }

    // ---- per-lane epilogue constants (L2-hot scalar loads) ----
    float bE[2], bR[2], wa[2], wf[2];
    #pragma unroll
    for (int nt = 0; nt < 2; ++nt) {
        const int h = n0 + nt * 16 + lm;
        bE[nt] = biasE[h]; bR[nt] = biasR[h]; wa[nt] = Wa[h]; wf[nt] = Wf2[h];
    }
    const int e_lane = (wv & 3) * 16 + lm;
    const float eh_be = be_[e_lane];
    const float eh_wf = Wf2[256 + e_lane];

    // ---- pass 1: attention logits, pure register + shfl ----
    float pa_lane[4];
    #pragma unroll
    for (int rg = 0; rg < 4; ++rg) {
        float s = 0.f;
        #pragma unroll
        for (int nt = 0; nt < 2; ++nt) {
            const float ev = accE[nt][rg] + bE[nt];
            const float rv = accR[nt][rg] + bR[nt];
            s = fmaf(tanhf_(ev + rv), wa[nt], s);
        }
        s += __shfl_xor(s, 1, 64); s += __shfl_xor(s, 2, 64);
        s += __shfl_xor(s, 4, 64); s += __shfl_xor(s, 8, 64);
        pa_lane[rg] = s;
    }

    __syncthreads();   // all staging-LDS reads complete; safe to overlay scratch
    if (lm == 0) {
        #pragma unroll
        for (int rg = 0; rg < 4; ++rg)
            pa_part[wv * 16 + lq * 4 + rg] = pa_lane[rg];
    }
    __syncthreads();
    if (tid < 16) {
        float t = ba[0];
        #pragma unroll
        for (int w = 0; w < 8; ++w) t += pa_part[w * 16 + tid];
        at_arr[tid] = sigmoidf_(t);
    }
    __syncthreads();

    // ---- pass 2: fused + EHR dot with Wf2, register + shfl ----
    float po_lane[4];
    #pragma unroll
    for (int rg = 0; rg < 4; ++rg) {
        const int r = lq * 4 + rg;
        const float at = at_arr[r];
        const float om = 1.f - at;
        float s = 0.f;
        #pragma unroll
        for (int nt = 0; nt < 2; ++nt) {
            const float ev = accE[nt][rg] + bE[nt];
            const float rv = accR[nt][rg] + bR[nt];
            s = fmaf(fmaxf(at * ev + om * rv, 0.f), wf[nt], s);
        }
        if (wv < 4)
            s = fmaf(fmaxf(accH[rg] + eh_be, 0.f), eh_wf, s);
        s += __shfl_xor(s, 1, 64); s += __shfl_xor(s, 2, 64);
        s += __shfl_xor(s, 4, 64); s += __shfl_xor(s, 8, 64);
        po_lane[rg] = s;
    }
    if (lm == 0) {
        #pragma unroll
        for (int rg = 0; rg < 4; ++rg)
            po_part[wv * 16 + lq * 4 + rg] = po_lane[rg];
    }
    __syncthreads();
    if (tid < 16) {
        float t = bf2[0];
        #pragma unroll
        for (int w = 0; w < 8; ++w) t += po_part[w * 16 + tid];
        out[row0 + tid] = sigmoidf_(t);
    }
}

// =====================================================================
extern "C" void kernel_launch(void* const* d_in, const int* in_sizes, int n_in,
                              void* d_out, int out_size, void* d_ws, size_t ws_size,
                              hipStream_t stream)
{
    (void)in_sizes; (void)n_in; (void)out_size; (void)ws_size;
    const float* ecc    = (const float*)d_in[0];
    const float* err    = (const float*)d_in[1];
    const float* ehr    = (const float*)d_in[2];
    const float* wt_ecc = (const float*)d_in[3];
    const float* bt_ecc = (const float*)d_in[4];
    const float* wt_err = (const float*)d_in[5];
    const float* bt_err = (const float*)d_in[6];
    const float* W0_ecc = (const float*)d_in[7];
    const float* W1_ecc = (const float*)d_in[8];
    const float* b_ecc  = (const float*)d_in[9];
    const float* W0_err = (const float*)d_in[10];
    const float* W1_err = (const float*)d_in[11];
    const float* b_err  = (const float*)d_in[12];
    const float* Wp_ecc = (const float*)d_in[13];
    const float* bp_ecc = (const float*)d_in[14];
    const float* Wp_err = (const float*)d_in[15];
    const float* bp_err = (const float*)d_in[16];
    const float* Wa     = (const float*)d_in[17];
    const float* ba     = (const float*)d_in[18];
    const float* We     = (const float*)d_in[19];
    const float* be     = (const float*)d_in[20];
    const float* Wf2    = (const float*)d_in[21];
    const float* bf2    = (const float*)d_in[22];
    float* wsf = (float*)d_ws;
    unsigned short* wsu = (unsigned short*)d_ws;
    float* out = (float*)d_out;

    fold_temporal<<<dim3(103), dim3(256), 0, stream>>>(
        wt_ecc, bt_ecc, wt_err, bt_err, W0_ecc, W1_ecc, b_ecc, W0_err, W1_err, b_err, wsf);
    fold_graph<<<dim3(MEP + MRP + 32 + 1), dim3(256), 0, stream>>>(
        Wp_ecc, bp_ecc, Wp_err, bp_err, We, wsf, wsu);
    fused_main<<<dim3(B_TOT / ROWS), dim3(512), 0, stream>>>(
        ecc, err, ehr, wsf, wsu, Wa, ba, be, Wf2, bf2, out);
}